// Round 10
// baseline (137.897 us; speedup 1.0000x reference)
//
#include <hip/hip_runtime.h>

#define N_ROWS 20000
#define T_DIM  512
#define K_DIM  12
#define TH_ROW ((T_DIM + 1) * K_DIM)   // 6156 floats per theta row
#define RPB    8                       // rows per block (4 waves x 2 rows)
#define NBLK   (N_ROWS / RPB)          // 2500 blocks

__device__ __forceinline__ float fast_rcp(float x) { return __builtin_amdgcn_rcpf(x); }

// transposed scan-buffer address for local t (pad 9 floats per 8)
__device__ __forceinline__ int tads(int tl) { return 9 * (tl >> 3) + (tl & 7); }

__device__ __forceinline__ void scan_chunk(
    const float* __restrict__ la, const float* __restrict__ lb,
    const float* __restrict__ lo, const float* __restrict__ le,
    int lane, int c, float s0, float& s_carry, float& e2_carry,
    float* __restrict__ sig_row, float& lsum)
{
    // lane owns local tl = 4*lane + i, i=0..3; tads(4*lane+i) == base+i (contiguous)
    const int base = 9 * (lane >> 1) + 4 * (lane & 1);
    float av[4], bv[4], ov[4], e2v[4];
    #pragma unroll
    for (int i = 0; i < 4; ++i) {
        av[i] = la[base + i]; bv[i] = lb[base + i];
        ov[i] = lo[base + i]; e2v[i] = le[base + i];
    }
    // e2 at tl-1 (previous element); lane 0 uses the inter-chunk carry
    float ep0 = e2_carry;
    if (lane > 0) ep0 = le[tads(4 * lane - 1)];

    float cv[4];
    cv[0] = fmaf(bv[0], ep0,    ov[0]);
    cv[1] = fmaf(bv[1], e2v[0], ov[1]);
    cv[2] = fmaf(bv[2], e2v[1], ov[2]);
    cv[3] = fmaf(bv[3], e2v[2], ov[3]);
    if (c == 0 && lane == 0) { av[0] = 0.f; cv[0] = s0; }   // sigma2[0] = s0

    // per-lane composite over its 4 steps: s_out = A*s_in + B
    float A = av[0], B = cv[0];
    #pragma unroll
    for (int i = 1; i < 4; ++i) { B = fmaf(av[i], B, cv[i]); A = av[i] * A; }

    // inclusive wave scan of affine composites (cur ∘ prev)
    float sA = A, sB = B;
    #pragma unroll
    for (int d = 1; d < 64; d <<= 1) {
        float Ap = __shfl_up(sA, d);
        float Bp = __shfl_up(sB, d);
        if (lane >= d) { sB = fmaf(sA, Bp, sB); sA = sA * Ap; }
    }
    // exclusive prefix -> sigma2 entering this lane's segment
    float exA = __shfl_up(sA, 1), exB = __shfl_up(sB, 1);
    if (lane == 0) { exA = 1.f; exB = 0.f; }
    float s = fmaf(exA, s_carry, exB);

    // replay: exact sequential recurrence within the lane's 4 steps
    #pragma unroll
    for (int i = 0; i < 4; ++i) {
        s = fmaf(av[i], s, cv[i]);
        sig_row[c * 256 + 4 * lane + i] = s;
        lsum += e2v[i] * fast_rcp(s) + __logf(s);
    }
    s_carry  = __shfl(s, 63);
    e2_carry = __shfl(e2v[3], 63);
}

// issue the first 4 load groups (13 coalesced loads) for a row
__device__ __forceinline__ void prologue_loads(
    const float* __restrict__ th_row, const float* __restrict__ y_row, int lane,
    float4 (&pv0)[4], float4 (&pv1)[4], float4 (&pv2)[4], float (&py)[4])
{
    #pragma unroll
    for (int i = 0; i < 4; ++i) {
        const int t = i * 64 + lane;
        const float4* p = (const float4*)(th_row + (size_t)(t + 1) * K_DIM);
        pv0[i] = p[0]; pv1[i] = p[1]; pv2[i] = p[2];
        py[i]  = y_row[t];
    }
}

// r3's phase-1: consume prefetched groups, keep depth-4 pipeline rolling
__device__ __forceinline__ void phase1(
    const float* __restrict__ th_row, const float* __restrict__ y_row, int lane,
    float4 (&pv0)[4], float4 (&pv1)[4], float4 (&pv2)[4], float (&py)[4],
    float* __restrict__ la, float* __restrict__ lb,
    float* __restrict__ lo, float* __restrict__ le,
    float* __restrict__ eps_row,
    float (&a1)[4], float (&b1)[4], float (&o1)[4], float (&e1)[4],
    float& osum, float& absum, const float* __restrict__ f)
{
    #pragma unroll
    for (int i = 0; i < 8; ++i) {
        const int slot = i & 3;
        const int t = i * 64 + lane;
        const float4 v0 = pv0[slot], v1 = pv1[slot], v2 = pv2[slot];
        const float  yv = py[slot];
        if (i < 4) {   // issue loads for iteration i+4
            const int t2 = (i + 4) * 64 + lane;
            const float4* p = (const float4*)(th_row + (size_t)(t2 + 1) * K_DIM);
            pv0[slot] = p[0]; pv1[slot] = p[1]; pv2[slot] = p[2];
            py[slot]  = y_row[t2];
            __builtin_amdgcn_sched_barrier(0);
        }
        const float* fp = &f[t * 9];
        float eps = yv - v0.x;
        eps = fmaf(-v0.y, fp[0], eps);
        eps = fmaf(-v0.z, fp[1], eps);
        eps = fmaf(-v0.w, fp[2], eps);
        eps = fmaf(-v1.x, fp[3], eps);
        eps = fmaf(-v1.y, fp[4], eps);
        eps = fmaf(-v1.z, fp[5], eps);
        eps = fmaf(-v1.w, fp[6], eps);
        eps = fmaf(-v2.x, fp[7], eps);
        eps_row[t] = eps;
        const float e2 = eps * eps;
        osum  += v2.w;
        absum += v2.y + v2.z;
        if (i < 4) {
            const int ad = tads(t);           // t < 256 in chunk 0
            la[ad] = v2.y; lb[ad] = v2.z; lo[ad] = v2.w; le[ad] = e2;
        } else {
            a1[slot] = v2.y; b1[slot] = v2.z; o1[slot] = v2.w; e1[slot] = e2;
        }
    }
}

__global__ __launch_bounds__(256, 4) void garch_kernel(
    const float* __restrict__ y,
    const float* __restrict__ f,
    const float* __restrict__ theta,
    float* __restrict__ ws_part,    // per-block loss partials (d_ws)
    float* __restrict__ out_eps,
    float* __restrict__ out_sig)
{
    __shared__ float lds_f[T_DIM * 9];        // f, stride-9 pad (conflict-free per-t reads)
    __shared__ float lds_scan[4][4 * 288];    // per-wave a/b/omega/e2, pad 9-per-8
    __shared__ float lds_part[4];

    const int tid = threadIdx.x;
    for (int idx = tid; idx < T_DIM * 8; idx += 256) {
        int t = idx >> 3, j = idx & 7;
        lds_f[t * 9 + j] = f[idx];
    }
    __syncthreads();

    const int wave = tid >> 6;
    const int lane = tid & 63;
    const int n0 = blockIdx.x * RPB + wave * 2;   // wave handles rows n0, n0+1

    float* const wb = &lds_scan[wave][0];
    float* const la = wb;
    float* const lb = wb + 288;
    float* const lo = wb + 576;
    float* const le = wb + 864;

    const float* th0 = theta + (size_t)n0 * TH_ROW;
    const float* y0  = y + (size_t)n0 * T_DIM;
    const float* th1 = th0 + TH_ROW;
    const float* y1  = y0 + T_DIM;
    float* eps0 = out_eps + (size_t)n0 * T_DIM;
    float* sig0 = out_sig + (size_t)n0 * T_DIM;
    float* eps1 = eps0 + T_DIM;
    float* sig1 = sig0 + T_DIM;

    float4 pv0[4], pv1[4], pv2[4];
    float  py[4];
    float a1[4], b1[4], o1[4], e1[4];
    float lsum = 0.f;

    // ================= row 0 =================
    prologue_loads(th0, y0, lane, pv0, pv1, pv2, py);
    __builtin_amdgcn_sched_barrier(0);

    float osum = 0.f, absum = 0.f;
    phase1(th0, y0, lane, pv0, pv1, pv2, py, la, lb, lo, le, eps0,
           a1, b1, o1, e1, osum, absum, lds_f);

    #pragma unroll
    for (int d = 32; d; d >>= 1) {
        osum  += __shfl_xor(osum, d);
        absum += __shfl_xor(absum, d);
    }
    float s0 = lo[0] + (la[0] + lb[0]) *
               ((osum * (1.0f / 512.0f)) / (1.0f - absum * (1.0f / 512.0f)));

    // hoist row-1 prologue: 13 KB of loads in flight across row-0's scan
    prologue_loads(th1, y1, lane, pv0, pv1, pv2, py);
    __builtin_amdgcn_sched_barrier(0);

    float s_carry = 0.f, e2_carry = 0.f;
    scan_chunk(la, lb, lo, le, lane, 0, s0, s_carry, e2_carry, sig0, lsum);
    #pragma unroll
    for (int i = 0; i < 4; ++i) {
        const int ad = tads(i * 64 + lane);
        la[ad] = a1[i]; lb[ad] = b1[i]; lo[ad] = o1[i]; le[ad] = e1[i];
    }
    scan_chunk(la, lb, lo, le, lane, 1, s0, s_carry, e2_carry, sig0, lsum);

    // ================= row 1 =================
    osum = 0.f; absum = 0.f;
    phase1(th1, y1, lane, pv0, pv1, pv2, py, la, lb, lo, le, eps1,
           a1, b1, o1, e1, osum, absum, lds_f);

    #pragma unroll
    for (int d = 32; d; d >>= 1) {
        osum  += __shfl_xor(osum, d);
        absum += __shfl_xor(absum, d);
    }
    s0 = lo[0] + (la[0] + lb[0]) *
         ((osum * (1.0f / 512.0f)) / (1.0f - absum * (1.0f / 512.0f)));

    s_carry = 0.f; e2_carry = 0.f;
    scan_chunk(la, lb, lo, le, lane, 0, s0, s_carry, e2_carry, sig1, lsum);
    #pragma unroll
    for (int i = 0; i < 4; ++i) {
        const int ad = tads(i * 64 + lane);
        la[ad] = a1[i]; lb[ad] = b1[i]; lo[ad] = o1[i]; le[ad] = e1[i];
    }
    scan_chunk(la, lb, lo, le, lane, 1, s0, s_carry, e2_carry, sig1, lsum);

    // ---------------- loss: block partial, no same-address atomics ----------------
    #pragma unroll
    for (int d = 32; d; d >>= 1) lsum += __shfl_xor(lsum, d);
    if (lane == 0) lds_part[wave] = lsum;
    __syncthreads();
    if (tid == 0) {
        ws_part[blockIdx.x] = lds_part[0] + lds_part[1] + lds_part[2] + lds_part[3];
    }
}

__global__ __launch_bounds__(1024) void reduce_kernel(
    const float* __restrict__ ws_part, float* __restrict__ out_loss)
{
    __shared__ float w[16];
    float s = 0.f;
    for (int i = threadIdx.x; i < NBLK; i += 1024) s += ws_part[i];
    #pragma unroll
    for (int d = 32; d; d >>= 1) s += __shfl_xor(s, d);
    const int wave = threadIdx.x >> 6, lane = threadIdx.x & 63;
    if (lane == 0) w[wave] = s;
    __syncthreads();
    if (threadIdx.x == 0) {
        float t = 0.f;
        #pragma unroll
        for (int i = 0; i < 16; ++i) t += w[i];
        out_loss[0] = t * (1.0f / ((float)N_ROWS * (float)T_DIM));
    }
}

extern "C" void kernel_launch(void* const* d_in, const int* in_sizes, int n_in,
                              void* d_out, int out_size, void* d_ws, size_t ws_size,
                              hipStream_t stream) {
    const float* y     = (const float*)d_in[0];
    const float* f     = (const float*)d_in[1];
    const float* theta = (const float*)d_in[2];
    float* out = (float*)d_out;
    float* ws  = (float*)d_ws;

    float* out_eps = out + 1;
    float* out_sig = out + 1 + (size_t)N_ROWS * T_DIM;

    garch_kernel<<<NBLK, 256, 0, stream>>>(y, f, theta, ws, out_eps, out_sig);
    reduce_kernel<<<1, 1024, 0, stream>>>(ws, out);
}

// Round 11
// 121.948 us; speedup vs baseline: 1.1308x; 1.1308x over previous
//
#include <hip/hip_runtime.h>

#define N_ROWS 20000
#define T_DIM  512
#define K_DIM  12
#define TH_ROW ((T_DIM + 1) * K_DIM)   // 6156 floats per theta row
#define GRID_B 1024                    // persistent: 4 blocks/CU exactly
#define NWAVE  (GRID_B * 4)            // 4096 persistent waves
#define NPART  GRID_B                  // one loss partial per block

__device__ __forceinline__ float fast_rcp(float x) { return __builtin_amdgcn_rcpf(x); }

// transposed scan-buffer address for local t (pad 9 floats per 8)
__device__ __forceinline__ int tads(int tl) { return 9 * (tl >> 3) + (tl & 7); }

__device__ __forceinline__ void scan_chunk(
    const float* __restrict__ la, const float* __restrict__ lb,
    const float* __restrict__ lo, const float* __restrict__ le,
    int lane, int c, float s0, float& s_carry, float& e2_carry,
    float* __restrict__ sig_row, float& lsum)
{
    // lane owns local tl = 4*lane + i, i=0..3; tads(4*lane+i) == base+i (contiguous)
    const int base = 9 * (lane >> 1) + 4 * (lane & 1);
    float av[4], bv[4], ov[4], e2v[4];
    #pragma unroll
    for (int i = 0; i < 4; ++i) {
        av[i] = la[base + i]; bv[i] = lb[base + i];
        ov[i] = lo[base + i]; e2v[i] = le[base + i];
    }
    // e2 at tl-1 (previous element); lane 0 uses the inter-chunk carry
    float ep0 = e2_carry;
    if (lane > 0) ep0 = le[tads(4 * lane - 1)];

    float cv[4];
    cv[0] = fmaf(bv[0], ep0,    ov[0]);
    cv[1] = fmaf(bv[1], e2v[0], ov[1]);
    cv[2] = fmaf(bv[2], e2v[1], ov[2]);
    cv[3] = fmaf(bv[3], e2v[2], ov[3]);
    if (c == 0 && lane == 0) { av[0] = 0.f; cv[0] = s0; }   // sigma2[0] = s0

    // per-lane composite over its 4 steps: s_out = A*s_in + B
    float A = av[0], B = cv[0];
    #pragma unroll
    for (int i = 1; i < 4; ++i) { B = fmaf(av[i], B, cv[i]); A = av[i] * A; }

    // inclusive wave scan of affine composites (cur ∘ prev)
    float sA = A, sB = B;
    #pragma unroll
    for (int d = 1; d < 64; d <<= 1) {
        float Ap = __shfl_up(sA, d);
        float Bp = __shfl_up(sB, d);
        if (lane >= d) { sB = fmaf(sA, Bp, sB); sA = sA * Ap; }
    }
    // exclusive prefix -> sigma2 entering this lane's segment
    float exA = __shfl_up(sA, 1), exB = __shfl_up(sB, 1);
    if (lane == 0) { exA = 1.f; exB = 0.f; }
    float s = fmaf(exA, s_carry, exB);

    // replay: exact sequential recurrence within the lane's 4 steps
    #pragma unroll
    for (int i = 0; i < 4; ++i) {
        s = fmaf(av[i], s, cv[i]);
        sig_row[c * 256 + 4 * lane + i] = s;
        lsum += e2v[i] * fast_rcp(s) + __logf(s);
    }
    s_carry  = __shfl(s, 63);
    e2_carry = __shfl(e2v[3], 63);
}

// issue the first 4 load groups (13 coalesced loads) for a row
__device__ __forceinline__ void prologue_loads(
    const float* __restrict__ th_row, const float* __restrict__ y_row, int lane,
    float4 (&pv0)[4], float4 (&pv1)[4], float4 (&pv2)[4], float (&py)[4])
{
    #pragma unroll
    for (int i = 0; i < 4; ++i) {
        const int t = i * 64 + lane;
        const float4* p = (const float4*)(th_row + (size_t)(t + 1) * K_DIM);
        pv0[i] = p[0]; pv1[i] = p[1]; pv2[i] = p[2];
        py[i]  = y_row[t];
    }
}

// r3's phase-1: consume prefetched groups, keep depth-4 pipeline rolling
__device__ __forceinline__ void phase1(
    const float* __restrict__ th_row, const float* __restrict__ y_row, int lane,
    float4 (&pv0)[4], float4 (&pv1)[4], float4 (&pv2)[4], float (&py)[4],
    float* __restrict__ la, float* __restrict__ lb,
    float* __restrict__ lo, float* __restrict__ le,
    float* __restrict__ eps_row,
    float (&a1)[4], float (&b1)[4], float (&o1)[4], float (&e1)[4],
    float& osum, float& absum, const float* __restrict__ f)
{
    #pragma unroll
    for (int i = 0; i < 8; ++i) {
        const int slot = i & 3;
        const int t = i * 64 + lane;
        const float4 v0 = pv0[slot], v1 = pv1[slot], v2 = pv2[slot];
        const float  yv = py[slot];
        if (i < 4) {   // issue loads for iteration i+4
            const int t2 = (i + 4) * 64 + lane;
            const float4* p = (const float4*)(th_row + (size_t)(t2 + 1) * K_DIM);
            pv0[slot] = p[0]; pv1[slot] = p[1]; pv2[slot] = p[2];
            py[slot]  = y_row[t2];
            __builtin_amdgcn_sched_barrier(0);
        }
        const float* fp = &f[t * 9];
        float eps = yv - v0.x;
        eps = fmaf(-v0.y, fp[0], eps);
        eps = fmaf(-v0.z, fp[1], eps);
        eps = fmaf(-v0.w, fp[2], eps);
        eps = fmaf(-v1.x, fp[3], eps);
        eps = fmaf(-v1.y, fp[4], eps);
        eps = fmaf(-v1.z, fp[5], eps);
        eps = fmaf(-v1.w, fp[6], eps);
        eps = fmaf(-v2.x, fp[7], eps);
        eps_row[t] = eps;
        const float e2 = eps * eps;
        osum  += v2.w;
        absum += v2.y + v2.z;
        if (i < 4) {
            const int ad = tads(t);           // t < 256 in chunk 0
            la[ad] = v2.y; lb[ad] = v2.z; lo[ad] = v2.w; le[ad] = e2;
        } else {
            a1[slot] = v2.y; b1[slot] = v2.z; o1[slot] = v2.w; e1[slot] = e2;
        }
    }
}

__global__ __launch_bounds__(256, 4) void garch_kernel(
    const float* __restrict__ y,
    const float* __restrict__ f,
    const float* __restrict__ theta,
    float* __restrict__ ws_part,    // per-block loss partials (d_ws)
    float* __restrict__ out_eps,
    float* __restrict__ out_sig)
{
    __shared__ float lds_f[T_DIM * 9];        // f, stride-9 pad (conflict-free per-t reads)
    __shared__ float lds_scan[4][4 * 288];    // per-wave a/b/omega/e2, pad 9-per-8
    __shared__ float lds_part[4];

    const int tid = threadIdx.x;
    for (int idx = tid; idx < T_DIM * 8; idx += 256) {
        int t = idx >> 3, j = idx & 7;
        lds_f[t * 9 + j] = f[idx];
    }
    __syncthreads();

    const int wave = tid >> 6;
    const int lane = tid & 63;
    const int wgid = blockIdx.x * 4 + wave;   // persistent wave id, 0..4095

    float* const wb = &lds_scan[wave][0];
    float* const la = wb;
    float* const lb = wb + 288;
    float* const lo = wb + 576;
    float* const le = wb + 864;

    float4 pv0[4], pv1[4], pv2[4];
    float  py[4];
    float a1[4], b1[4], o1[4], e1[4];
    float lsum = 0.f;

    // prologue for row k=0 (wgid < 4096 < N_ROWS always valid)
    prologue_loads(theta + (size_t)wgid * TH_ROW, y + (size_t)wgid * T_DIM,
                   lane, pv0, pv1, pv2, py);
    __builtin_amdgcn_sched_barrier(0);

    #pragma unroll 1
    for (int k = 0; k < 5; ++k) {
        const int n = wgid + k * NWAVE;
        if (n < N_ROWS) {                     // wave-uniform guard (wgid uniform)
            const float* th_row = theta + (size_t)n * TH_ROW;
            const float* y_row  = y + (size_t)n * T_DIM;
            float* eps_row = out_eps + (size_t)n * T_DIM;
            float* sig_row = out_sig + (size_t)n * T_DIM;

            float osum = 0.f, absum = 0.f;
            phase1(th_row, y_row, lane, pv0, pv1, pv2, py,
                   la, lb, lo, le, eps_row, a1, b1, o1, e1, osum, absum, lds_f);

            #pragma unroll
            for (int d = 32; d; d >>= 1) {
                osum  += __shfl_xor(osum, d);
                absum += __shfl_xor(absum, d);
            }
            const float s0 = lo[0] + (la[0] + lb[0]) *
                ((osum * (1.0f / 512.0f)) / (1.0f - absum * (1.0f / 512.0f)));

            // hoist NEXT row's prologue: 13 KB of loads in flight across this scan
            const int n2 = n + NWAVE;
            if (n2 < N_ROWS) {
                prologue_loads(theta + (size_t)n2 * TH_ROW, y + (size_t)n2 * T_DIM,
                               lane, pv0, pv1, pv2, py);
                __builtin_amdgcn_sched_barrier(0);
            }

            float s_carry = 0.f, e2_carry = 0.f;
            scan_chunk(la, lb, lo, le, lane, 0, s0, s_carry, e2_carry, sig_row, lsum);
            #pragma unroll
            for (int i = 0; i < 4; ++i) {
                const int ad = tads(i * 64 + lane);
                la[ad] = a1[i]; lb[ad] = b1[i]; lo[ad] = o1[i]; le[ad] = e1[i];
            }
            scan_chunk(la, lb, lo, le, lane, 1, s0, s_carry, e2_carry, sig_row, lsum);
        }
    }

    // ---------------- loss: block partial, no same-address atomics ----------------
    #pragma unroll
    for (int d = 32; d; d >>= 1) lsum += __shfl_xor(lsum, d);
    if (lane == 0) lds_part[wave] = lsum;
    __syncthreads();
    if (tid == 0) {
        ws_part[blockIdx.x] = lds_part[0] + lds_part[1] + lds_part[2] + lds_part[3];
    }
}

__global__ __launch_bounds__(1024) void reduce_kernel(
    const float* __restrict__ ws_part, float* __restrict__ out_loss)
{
    __shared__ float w[16];
    float s = 0.f;
    for (int i = threadIdx.x; i < NPART; i += 1024) s += ws_part[i];
    #pragma unroll
    for (int d = 32; d; d >>= 1) s += __shfl_xor(s, d);
    const int wave = threadIdx.x >> 6, lane = threadIdx.x & 63;
    if (lane == 0) w[wave] = s;
    __syncthreads();
    if (threadIdx.x == 0) {
        float t = 0.f;
        #pragma unroll
        for (int i = 0; i < 16; ++i) t += w[i];
        out_loss[0] = t * (1.0f / ((float)N_ROWS * (float)T_DIM));
    }
}

extern "C" void kernel_launch(void* const* d_in, const int* in_sizes, int n_in,
                              void* d_out, int out_size, void* d_ws, size_t ws_size,
                              hipStream_t stream) {
    const float* y     = (const float*)d_in[0];
    const float* f     = (const float*)d_in[1];
    const float* theta = (const float*)d_in[2];
    float* out = (float*)d_out;
    float* ws  = (float*)d_ws;

    float* out_eps = out + 1;
    float* out_sig = out + 1 + (size_t)N_ROWS * T_DIM;

    garch_kernel<<<GRID_B, 256, 0, stream>>>(y, f, theta, ws, out_eps, out_sig);
    reduce_kernel<<<1, 1024, 0, stream>>>(ws, out);
}